// Round 2
// baseline (230.414 us; speedup 1.0000x reference)
//
#include <hip/hip_runtime.h>

#define EPS_ 1e-5f
#define BATCH 32
#define CIN 240
#define H_ 56
#define W_ 56
#define HW 3136          // 56*56, divisible by 64
#define C1 24            // init_c
#define R_ 9             // ratio-1
#define C2 216           // C1*R_
#define COUT 240

// ---- workspace layout (floats) ---- total 6464 floats (~26 KB)
#define WS_WT   0        // [240][24]  conv1x1 weights, ci-major, BN1 scale folded
#define WS_B1   5760     // [24]       BN1 bias
#define WS_WDW  5784     // [24][9]    dw weights, BN2 scale folded
#define WS_B2   6000     // [24]       BN2 bias
#define WS_INV3 6024     // [216]
#define WS_T3   6240     // [216]
// t1 (conv1x1+BN1 intermediate) lives in OUT channels [24,48) -- dead space
// until the adder kernel overwrites them (stream-ordered, read set disjoint
// from write set in every kernel).

__global__ __launch_bounds__(256) void prep_kernel(
    const float* __restrict__ wp,
    const float* __restrict__ g1, const float* __restrict__ b1,
    const float* __restrict__ m1, const float* __restrict__ v1,
    const float* __restrict__ wdw,
    const float* __restrict__ g2, const float* __restrict__ b2,
    const float* __restrict__ m2, const float* __restrict__ v2,
    const float* __restrict__ g3, const float* __restrict__ b3,
    const float* __restrict__ m3, const float* __restrict__ v3,
    float* __restrict__ ws) {
  int i = blockIdx.x * 256 + threadIdx.x;
  if (i < 5760) {
    // transpose w_primary (co-major [24][240]) -> ci-major [240][24], fold BN1
    int ci = i / C1, co = i % C1;
    float s = g1[co] / sqrtf(v1[co] + EPS_);
    ws[WS_WT + ci * C1 + co] = wp[co * CIN + ci] * s;
    if (ci == 0) ws[WS_B1 + co] = b1[co] - m1[co] * s;
  } else if (i < 5760 + C2) {
    int j = i - 5760;           // [0,216): c*9+k
    int c = j / 9;
    float s = g2[c] / sqrtf(v2[c] + EPS_);
    ws[WS_WDW + j] = wdw[j] * s;
    if (j % 9 == 0) ws[WS_B2 + c] = b2[c] - m2[c] * s;
  } else if (i < 5976 + C2) {
    int j = i - 5976;           // [0,216)
    float s = g3[j] / sqrtf(v3[j] + EPS_);
    ws[WS_INV3 + j] = s;
    ws[WS_T3 + j] = b3[j] - m3[j] * s;
  }
}

// 1x1 conv (240 -> 24) + BN1. One thread per (b,hw) pixel, 24 reg accumulators.
// Writes t1 into out channels [24,48).
__global__ __launch_bounds__(256) void conv1x1_kernel(
    const float* __restrict__ x, const float* __restrict__ wt,
    const float* __restrict__ bias1, float* __restrict__ out) {
  int p  = blockIdx.x * 256 + threadIdx.x;  // [0, 100352)
  int b  = p / HW;
  int hw = p - b * HW;
  const float* xb = x + (size_t)b * CIN * HW + hw;

  float acc[C1];
#pragma unroll
  for (int co = 0; co < C1; ++co) acc[co] = 0.f;

#pragma unroll 8
  for (int ci = 0; ci < CIN; ++ci) {
    float xv = xb[(size_t)ci * HW];
    const float* wr = wt + ci * C1;
#pragma unroll
    for (int co = 0; co < C1; ++co) acc[co] = fmaf(wr[co], xv, acc[co]);
  }

  float* o = out + ((size_t)b * COUT + C1) * HW + hw;   // channels [24,48)
#pragma unroll
  for (int co = 0; co < C1; ++co) o[(size_t)co * HW] = acc[co] + bias1[co];
}

// depthwise 3x3 conv + BN2: reads t1 from out ch [24,48), writes x1 to ch [0,24)
__global__ __launch_bounds__(256) void dw_kernel(
    const float* __restrict__ outr, const float* __restrict__ wdwf,
    const float* __restrict__ bias2, float* __restrict__ out) {
  int p = blockIdx.x * 256 + threadIdx.x;
  if (p >= HW) return;
  int c = blockIdx.y, b = blockIdx.z;
  int h = p / W_, w = p - h * W_;
  const float* in = outr + ((size_t)b * COUT + C1 + c) * HW;
  const float* wk = wdwf + c * 9;
  float acc = bias2[c];
#pragma unroll
  for (int kh = 0; kh < 3; ++kh) {
    int hh = h + kh - 1;
    if (hh < 0 || hh >= H_) continue;
#pragma unroll
    for (int kw = 0; kw < 3; ++kw) {
      int ww = w + kw - 1;
      if (ww < 0 || ww >= W_) continue;
      acc = fmaf(in[hh * W_ + ww], wk[kh * 3 + kw], acc);
    }
  }
  out[((size_t)b * COUT + c) * HW + p] = acc;
}

// adder depthwise (24 -> 216) + BN3 + ReLU: reads x1 from out ch [0,24),
// writes x2 to out ch [24,240).
// NOTE: reference pads x1 with zeros and still takes |0 - tap| at borders,
// so OOB positions contribute fabsf(tap) -- we load 0 and never skip taps.
__global__ __launch_bounds__(256) void adder_kernel(
    const float* __restrict__ outr, const float* __restrict__ wadd,
    const float* __restrict__ inv3, const float* __restrict__ t3,
    float* __restrict__ out) {
  int p = blockIdx.x * 256 + threadIdx.x;
  if (p >= HW) return;
  int c = blockIdx.y, b = blockIdx.z;
  int h = p / W_, w = p - h * W_;
  const float* in = outr + ((size_t)b * COUT + c) * HW;

  float xv[9];
#pragma unroll
  for (int kh = 0; kh < 3; ++kh) {
#pragma unroll
    for (int kw = 0; kw < 3; ++kw) {
      int hh = h + kh - 1, ww = w + kw - 1;
      bool ok = (hh >= 0) & (hh < H_) & (ww >= 0) & (ww < W_);
      xv[kh * 3 + kw] = ok ? in[hh * W_ + ww] : 0.f;
    }
  }

#pragma unroll
  for (int r = 0; r < R_; ++r) {
    int j = c * R_ + r;                 // channel within the 216
    const float* tp = wadd + j * 9;     // w_add[c][r][.]
    float acc = 0.f;
#pragma unroll
    for (int k = 0; k < 9; ++k) acc += fabsf(xv[k] - tp[k]);
    float y = fmaf(-inv3[j], acc, t3[j]);
    out[((size_t)b * COUT + (C1 + j)) * HW + p] = fmaxf(y, 0.f);
  }
}

extern "C" void kernel_launch(void* const* d_in, const int* in_sizes, int n_in,
                              void* d_out, int out_size, void* d_ws, size_t ws_size,
                              hipStream_t stream) {
  const float* x    = (const float*)d_in[0];
  const float* wp   = (const float*)d_in[1];
  const float* g1   = (const float*)d_in[2];
  const float* b1   = (const float*)d_in[3];
  const float* m1   = (const float*)d_in[4];
  const float* v1   = (const float*)d_in[5];
  const float* wdw  = (const float*)d_in[6];
  const float* g2   = (const float*)d_in[7];
  const float* b2   = (const float*)d_in[8];
  const float* m2   = (const float*)d_in[9];
  const float* v2   = (const float*)d_in[10];
  const float* wadd = (const float*)d_in[11];
  const float* g3   = (const float*)d_in[12];
  const float* b3   = (const float*)d_in[13];
  const float* m3   = (const float*)d_in[14];
  const float* v3   = (const float*)d_in[15];

  float* ws  = (float*)d_ws;
  float* out = (float*)d_out;

  // fold BN params / transpose weights (~26 KB of ws)
  prep_kernel<<<25, 256, 0, stream>>>(wp, g1, b1, m1, v1, wdw, g2, b2, m2, v2,
                                      g3, b3, m3, v3, ws);

  // 1x1 conv + BN1 -> t1 in out channels [24,48). 392*256 == 32*3136.
  conv1x1_kernel<<<392, 256, 0, stream>>>(x, ws + WS_WT, ws + WS_B1, out);

  // dw 3x3 + BN2: t1 (ch 24..47) -> x1 (ch 0..23)
  dw_kernel<<<dim3(13, C1, BATCH), 256, 0, stream>>>(out, ws + WS_WDW,
                                                     ws + WS_B2, out);

  // adder + BN3 + ReLU: x1 (ch 0..23) -> x2 (ch 24..239)
  adder_kernel<<<dim3(13, C1, BATCH), 256, 0, stream>>>(out, wadd, ws + WS_INV3,
                                                        ws + WS_T3, out);
}